// Round 1
// 506.890 us; speedup vs baseline: 1.0242x; 1.0242x over previous
//
#include <hip/hip_runtime.h>
#include <cstdint>
#include <cstddef>

#define H_  16
#define V_  8
#define DH_ 128
#define B_  4096
#define BT  16      // batch rows per block
#define LDST 132    // padded LDS row stride (floats)

// ---------------------------------------------------------------------------
// Kernel A: precompute M[h] = Wq[h]^T @ Wk[h]   (layout M[h][d][d'])
//           and      NT[h] = (Wo[h] @ Wv[h])^T  (layout NT[h][d'][e])
// grid = 2*H*64 = 2048 blocks, 256 threads: one output row-pair per block.
// 8 blocks/CU -> latency hidden by TLP (old version was 1 block/CU).
// ---------------------------------------------------------------------------
__global__ __launch_bounds__(256) void precompute_MN(
    const float* __restrict__ Wq, const float* __restrict__ Wk,
    const float* __restrict__ Wv, const float* __restrict__ Wo,
    float* __restrict__ Mmat, float* __restrict__ NTmat)
{
    const int bx    = blockIdx.x;
    const int which = bx & 1;
    const int h     = (bx >> 1) & 15;
    const int chunk = bx >> 5;              // 0..63
    const int tid   = threadIdx.x;
    const int col   = tid & 127;            // d' 0..127
    const int r     = chunk * 2 + (tid >> 7); // row 0..127

    float acc = 0.f;
    if (which == 0) {
        // M[d][d'] = sum_e Wq[e][d] * Wk[e][d'];  row=d=r, col=d'
        const float* wq = Wq + h * DH_ * DH_;
        const float* wk = Wk + h * DH_ * DH_;
#pragma unroll 8
        for (int e = 0; e < DH_; ++e)
            acc += wq[e * DH_ + r] * wk[e * DH_ + col];  // uniform * coalesced
        Mmat[h * DH_ * DH_ + (size_t)r * DH_ + col] = acc;
    } else {
        // N2[e][d'] = sum_d Wo[e][d] * Wv[d][d'];  row=e=r, col=d'
        // stored TRANSPOSED: NT[d'][e] so phase-3 streaming stays coalesced.
        const float* wo = Wo + h * DH_ * DH_;
        const float* wv = Wv + h * DH_ * DH_;
#pragma unroll 8
        for (int d = 0; d < DH_; ++d)
            acc += wo[(size_t)r * DH_ + d] * wv[d * DH_ + col]; // uniform * coalesced
        NTmat[h * DH_ * DH_ + (size_t)col * DH_ + r] = acc;     // scattered, tiny
    }
}

// ---------------------------------------------------------------------------
// Kernel B: fused per-(b,h) pipeline, 2-wave blocks for max residency.
//   qk  = iso @ M           (16x128 = 16x128 @ 128x128, reg-tiled 4x4)
//   s_v = qk . view[v] / sqrt(DH) + log(pi+eps); attn = softmax_v
//   ctx = sum_v attn[v] * view[v]
//   out = ctx @ NT          (reg-tiled 4x4)
// grid = H * (B/BT) = 4096 blocks, 128 threads (2 waves).
// LDS 9.5 KB (single reused 16x132 buffer) + VGPR<=64 -> 16 blocks/CU,
// 32 waves/CU, whole grid resident in one round; 16 phase-staggered blocks
// per CU overlap view streaming with the two matmul phases.
// ---------------------------------------------------------------------------
__global__ __launch_bounds__(128, 8) void fused_attn(
    const float* __restrict__ iso, const float* __restrict__ view,
    const float* __restrict__ pi,
    const float* __restrict__ Mmat, const float* __restrict__ NTmat,
    float* __restrict__ out, float* __restrict__ attn_out)
{
    __shared__ float buf_s[BT][LDST];   // iso tile -> qk -> ctx (reused)
    __shared__ float sc_s[BT][V_];      // raw scores (dot only)
    __shared__ float at_s[BT][V_];      // attention weights

    const int tid = threadIdx.x;               // 0..127
    const int h   = blockIdx.x >> 8;           // 256 b-tiles per head
    const int b0  = (blockIdx.x & 255) * BT;

    // ---- stage iso tile: 16 rows x 128 floats, coalesced float4 loads
#pragma unroll
    for (int i = 0; i < 4; ++i) {
        const int idx = tid + i * 128;         // 512 float4 total
        const int b   = idx >> 5;              // 32 float4 per row
        const int dq  = idx & 31;
        const float4 v4 = *(const float4*)(iso + ((size_t)(b0 + b) * H_ + h) * DH_ + dq * 4);
        *(float4*)&buf_s[b][dq * 4] = v4;
    }
    __syncthreads();

    const int tx = tid & 31;                   // output-col quad (d' = tx*4..+3)
    const int ty = tid >> 5;                   // output-row group (b = ty*4..+3)

    float acc[4][4];

    // ---- phase 1: qk[b][d'] = sum_d iso[b][d] * M[d][d']
    {
        const float* Mh = Mmat + h * DH_ * DH_ + tx * 4;
#pragma unroll
        for (int i = 0; i < 4; ++i)
#pragma unroll
            for (int j = 0; j < 4; ++j) acc[i][j] = 0.f;

        for (int d = 0; d < DH_; d += 4) {
            const float4 m0 = *(const float4*)(Mh + (size_t)(d + 0) * DH_);
            const float4 m1 = *(const float4*)(Mh + (size_t)(d + 1) * DH_);
            const float4 m2 = *(const float4*)(Mh + (size_t)(d + 2) * DH_);
            const float4 m3 = *(const float4*)(Mh + (size_t)(d + 3) * DH_);
#pragma unroll
            for (int i = 0; i < 4; ++i) {
                const float4 a = *(const float4*)&buf_s[ty * 4 + i][d];
                acc[i][0] += a.x * m0.x + a.y * m1.x + a.z * m2.x + a.w * m3.x;
                acc[i][1] += a.x * m0.y + a.y * m1.y + a.z * m2.y + a.w * m3.y;
                acc[i][2] += a.x * m0.z + a.y * m1.z + a.z * m2.z + a.w * m3.z;
                acc[i][3] += a.x * m0.w + a.y * m1.w + a.z * m2.w + a.w * m3.w;
            }
        }
    }
    __syncthreads();   // all iso reads done; buf_s safe to overwrite

    // ---- write qk over the (dead) iso tile
#pragma unroll
    for (int i = 0; i < 4; ++i)
        *(float4*)&buf_s[ty * 4 + i][tx * 4] =
            make_float4(acc[i][0], acc[i][1], acc[i][2], acc[i][3]);
    __syncthreads();   // qk visible to all

    // ---- phase 2a: scores. Half-wave (32 lanes) per view row, coalesced.
    // wave w handles pairs p = w*64 + it*2 + half, p -> (b = p>>3, v = p&7)
    {
        const int wv_  = tid >> 6;             // wave id 0/1
        const int lane = tid & 63;
        const int half = lane >> 5;            // 0/1: which row of the pair
        const int l32  = lane & 31;            // d-chunk: floats l32*4..+3
#pragma unroll 4
        for (int it = 0; it < 32; ++it) {
            const int p  = wv_ * 64 + it * 2 + half;   // 0..127
            const int bl = p >> 3;
            const int v  = p & 7;
            const float4 w = *(const float4*)(view +
                (((size_t)(b0 + bl) * H_ + h) * V_ + v) * DH_ + l32 * 4);
            const float4 q = *(const float4*)&buf_s[bl][l32 * 4];
            float s = w.x * q.x + w.y * q.y + w.z * q.z + w.w * q.w;
            // reduce across the 32-lane half (xor masks stay within the half)
            s += __shfl_xor(s, 1);
            s += __shfl_xor(s, 2);
            s += __shfl_xor(s, 4);
            s += __shfl_xor(s, 8);
            s += __shfl_xor(s, 16);
            if (l32 == 0) sc_s[bl][v] = s;
        }
    }
    __syncthreads();   // raw scores ready

    // ---- phase 2a': softmax. one thread per (b, v): 16*8 = 128
    {
        const int bl = tid >> 3;
        const int v  = tid & 7;
        float sc = sc_s[bl][v] * 0.08838834764831845f;   // 1/sqrt(128)
        sc += logf(pi[((size_t)(b0 + bl) * H_ + h) * V_ + v] + 1e-6f);

        // softmax across the 8 v-lanes (contiguous within the wave)
        float mx = sc;
        mx = fmaxf(mx, __shfl_xor(mx, 1));
        mx = fmaxf(mx, __shfl_xor(mx, 2));
        mx = fmaxf(mx, __shfl_xor(mx, 4));
        const float ex = expf(sc - mx);
        float sm = ex;
        sm += __shfl_xor(sm, 1);
        sm += __shfl_xor(sm, 2);
        sm += __shfl_xor(sm, 4);
        const float at = ex / sm;
        at_s[bl][v] = at;
        attn_out[((size_t)(b0 + bl) * H_ + h) * V_ + v] = at;
    }
    __syncthreads();   // attn ready; qk dead

    // ---- phase 2b: ctx[b][d'] = sum_v attn[v]*view[b,h,v,d'] -> buf_s
    // 32 lanes per b-row, lane owns d' = l32*4..+3. view rows hit L2/L3.
    {
        const int bg  = tid >> 5;              // 0..3: row within group of 4
        const int l32 = tid & 31;
#pragma unroll
        for (int r = 0; r < 4; ++r) {
            const int b = r * 4 + bg;
            const float* vbase = view + (((size_t)(b0 + b) * H_ + h) * V_) * DH_ + l32 * 4;
            float4 c = make_float4(0.f, 0.f, 0.f, 0.f);
#pragma unroll
            for (int vv = 0; vv < V_; ++vv) {
                const float a = at_s[b][vv];                 // LDS broadcast
                const float4 x = *(const float4*)(vbase + (size_t)vv * DH_);
                c.x += a * x.x; c.y += a * x.y; c.z += a * x.z; c.w += a * x.w;
            }
            *(float4*)&buf_s[b][l32 * 4] = c;
        }
    }
    __syncthreads();   // ctx ready

    // ---- phase 3: out[b][e] = sum_d' ctx[b][d'] * NT[d'][e]
    {
        const float* Nh = NTmat + h * DH_ * DH_ + tx * 4;
#pragma unroll
        for (int i = 0; i < 4; ++i)
#pragma unroll
            for (int j = 0; j < 4; ++j) acc[i][j] = 0.f;

        for (int dp = 0; dp < DH_; dp += 4) {
            const float4 n0 = *(const float4*)(Nh + (size_t)(dp + 0) * DH_);
            const float4 n1 = *(const float4*)(Nh + (size_t)(dp + 1) * DH_);
            const float4 n2 = *(const float4*)(Nh + (size_t)(dp + 2) * DH_);
            const float4 n3 = *(const float4*)(Nh + (size_t)(dp + 3) * DH_);
#pragma unroll
            for (int i = 0; i < 4; ++i) {
                const float4 a = *(const float4*)&buf_s[ty * 4 + i][dp];
                acc[i][0] += a.x * n0.x + a.y * n1.x + a.z * n2.x + a.w * n3.x;
                acc[i][1] += a.x * n0.y + a.y * n1.y + a.z * n2.y + a.w * n3.y;
                acc[i][2] += a.x * n0.z + a.y * n1.z + a.z * n2.z + a.w * n3.z;
                acc[i][3] += a.x * n0.w + a.y * n1.w + a.z * n2.w + a.w * n3.w;
            }
        }
#pragma unroll
        for (int i = 0; i < 4; ++i)
            *(float4*)(out + ((size_t)(b0 + ty * 4 + i) * H_ + h) * DH_ + tx * 4) =
                make_float4(acc[i][0], acc[i][1], acc[i][2], acc[i][3]);
    }
}

// ---------------------------------------------------------------------------
extern "C" void kernel_launch(void* const* d_in, const int* in_sizes, int n_in,
                              void* d_out, int out_size, void* d_ws, size_t ws_size,
                              hipStream_t stream)
{
    const float* iso  = (const float*)d_in[0];   // [B,H,DH]
    const float* view = (const float*)d_in[1];   // [B,H,V,DH]
    const float* pi   = (const float*)d_in[2];   // [B,H,V]
    const float* Wq   = (const float*)d_in[3];   // [H,DH,DH]
    const float* Wk   = (const float*)d_in[4];
    const float* Wv   = (const float*)d_in[5];
    const float* Wo   = (const float*)d_in[6];

    float* out  = (float*)d_out;                           // [B,H,DH]
    float* attn = out + (size_t)B_ * H_ * DH_;             // [B,H,V]

    float* Mmat  = (float*)d_ws;                           // H*DH*DH floats (1 MB)
    float* NTmat = Mmat + (size_t)H_ * DH_ * DH_;          // H*DH*DH floats (1 MB)

    hipLaunchKernelGGL(precompute_MN, dim3(2048), dim3(256), 0, stream,
                       Wq, Wk, Wv, Wo, Mmat, NTmat);
    hipLaunchKernelGGL(fused_attn, dim3(H_ * (B_ / BT)), dim3(128), 0, stream,
                       iso, view, pi, Mmat, NTmat, out, attn);
}

// Round 2
// 484.836 us; speedup vs baseline: 1.0707x; 1.0455x over previous
//
#include <hip/hip_runtime.h>
#include <cstdint>
#include <cstddef>

#define H_  16
#define V_  8
#define DH_ 128
#define B_  4096
#define BT  32      // batch rows per block
#define LDST 132    // padded LDS row stride (floats)

// ---------------------------------------------------------------------------
// Kernel A: precompute M[h] = Wq[h]^T @ Wk[h]   (layout M[h][d][d'])
//           and      NT[h] = (Wo[h] @ Wv[h])^T  (layout NT[h][d'][e])
// grid = 2048 blocks, 256 threads: one output row-pair per block.
// ---------------------------------------------------------------------------
__global__ __launch_bounds__(256) void precompute_MN(
    const float* __restrict__ Wq, const float* __restrict__ Wk,
    const float* __restrict__ Wv, const float* __restrict__ Wo,
    float* __restrict__ Mmat, float* __restrict__ NTmat)
{
    const int bx    = blockIdx.x;
    const int which = bx & 1;
    const int h     = (bx >> 1) & 15;
    const int chunk = bx >> 5;              // 0..63
    const int tid   = threadIdx.x;
    const int col   = tid & 127;            // d' 0..127
    const int r     = chunk * 2 + (tid >> 7); // row 0..127

    float acc = 0.f;
    if (which == 0) {
        // M[d][d'] = sum_e Wq[e][d] * Wk[e][d'];  row=d=r, col=d'
        const float* wq = Wq + h * DH_ * DH_;
        const float* wk = Wk + h * DH_ * DH_;
#pragma unroll 8
        for (int e = 0; e < DH_; ++e)
            acc += wq[e * DH_ + r] * wk[e * DH_ + col];  // uniform * coalesced
        Mmat[h * DH_ * DH_ + (size_t)r * DH_ + col] = acc;
    } else {
        // N2[e][d'] = sum_d Wo[e][d] * Wv[d][d'];  row=e=r, col=d'
        // stored TRANSPOSED: NT[d'][e] so phase-3 streaming stays coalesced.
        const float* wo = Wo + h * DH_ * DH_;
        const float* wv = Wv + h * DH_ * DH_;
#pragma unroll 8
        for (int d = 0; d < DH_; ++d)
            acc += wo[(size_t)r * DH_ + d] * wv[d * DH_ + col]; // uniform * coalesced
        NTmat[h * DH_ * DH_ + (size_t)col * DH_ + r] = acc;     // scattered, tiny
    }
}

// ---------------------------------------------------------------------------
// Kernel B: fused per-(b,h) pipeline, weight-stationary via LDS.
//   Phases 1/3 read M / NT from LDS (staged in 32KB halves into one buffer),
//   killing the 1 GB of per-wave L2 weight re-reads that round-1 counters
//   showed as the latency bottleneck (all pipes <25% at 80% occupancy).
//   Middle phase (scores/softmax/ctx) is wave-private: wave w owns rows
//   8w..8w+7; qk and ctx for those rows never cross waves -> no barriers.
// grid = H * (B/BT) = 2048 blocks, 256 threads (4 waves), 3 blocks/CU.
// ---------------------------------------------------------------------------
__global__ __launch_bounds__(256, 3) void fused_attn(
    const float* __restrict__ iso, const float* __restrict__ view,
    const float* __restrict__ pi,
    const float* __restrict__ Mmat, const float* __restrict__ NTmat,
    float* __restrict__ out, float* __restrict__ attn_out)
{
    __shared__ float wbuf[64 * DH_];     // 32 KB: M-lo -> M-hi -> NT-lo -> NT-hi
    __shared__ float row_s[BT][LDST];    // iso tile -> qk -> ctx (wave-private rows)
    __shared__ float at_s[BT][V_];       // attention weights

    const int tid = threadIdx.x;
    const int h   = blockIdx.x >> 7;            // 128 b-tiles per head
    const int b0  = (blockIdx.x & 127) * BT;

    const int tx = tid & 31;                    // output-col quad (4 cols)
    const int ty = tid >> 5;                    // 0..7: row group (4 rows)

    const float* Mh = Mmat  + (size_t)h * DH_ * DH_;
    const float* Nh = NTmat + (size_t)h * DH_ * DH_;

    // ---- stage iso tile (32x128, padded) + M-lo (rows 0..63, linear)
#pragma unroll
    for (int i = 0; i < 4; ++i) {
        const int idx = tid + i * 256;          // 1024 float4
        const int r   = idx >> 5;
        const int q   = idx & 31;
        *(float4*)&row_s[r][q * 4] =
            *(const float4*)(iso + ((size_t)(b0 + r) * H_ + h) * DH_ + q * 4);
    }
#pragma unroll
    for (int i = 0; i < 8; ++i) {
        const int idx = tid + i * 256;          // 2048 float4 = 32 KB
        *(float4*)&wbuf[idx * 4] = *(const float4*)(Mh + (size_t)idx * 4);
    }
    __syncthreads();

    float acc[4][4];
#pragma unroll
    for (int i = 0; i < 4; ++i)
#pragma unroll
        for (int j = 0; j < 4; ++j) acc[i][j] = 0.f;

    // 64-row MAC section: acc[i][j] += row_s[ty*4+i][dbase+dd] * wbuf[dd][tx*4+j]
    auto mac64 = [&](int dbase) {
#pragma unroll 4
        for (int dd = 0; dd < 64; dd += 4) {
            const float4 m0 = *(const float4*)&wbuf[(dd + 0) * DH_ + tx * 4];
            const float4 m1 = *(const float4*)&wbuf[(dd + 1) * DH_ + tx * 4];
            const float4 m2 = *(const float4*)&wbuf[(dd + 2) * DH_ + tx * 4];
            const float4 m3 = *(const float4*)&wbuf[(dd + 3) * DH_ + tx * 4];
#pragma unroll
            for (int i = 0; i < 4; ++i) {
                const float4 a = *(const float4*)&row_s[ty * 4 + i][dbase + dd];
                acc[i][0] += a.x * m0.x + a.y * m1.x + a.z * m2.x + a.w * m3.x;
                acc[i][1] += a.x * m0.y + a.y * m1.y + a.z * m2.y + a.w * m3.y;
                acc[i][2] += a.x * m0.z + a.y * m1.z + a.z * m2.z + a.w * m3.z;
                acc[i][3] += a.x * m0.w + a.y * m1.w + a.z * m2.w + a.w * m3.w;
            }
        }
    };

    // ---- phase 1a: iso cols 0..63 x M rows 0..63
    mac64(0);
    __syncthreads();                            // done reading M-lo

    // ---- stage M-hi (rows 64..127)
#pragma unroll
    for (int i = 0; i < 8; ++i) {
        const int idx = tid + i * 256;
        *(float4*)&wbuf[idx * 4] = *(const float4*)(Mh + 8192 + (size_t)idx * 4);
    }
    __syncthreads();

    // ---- phase 1b: iso cols 64..127 x M rows 64..127
    mac64(64);

    // ---- qk overwrite of iso rows: wave-private (rows ty*4.. are in-wave)
#pragma unroll
    for (int i = 0; i < 4; ++i)
        *(float4*)&row_s[ty * 4 + i][tx * 4] =
            make_float4(acc[i][0], acc[i][1], acc[i][2], acc[i][3]);

    // ---- middle: scores + softmax + ctx, fully wave-private (no barriers)
    {
        const int w    = tid >> 6;              // wave 0..3, owns rows w*8..w*8+7
        const int lane = tid & 63;
        const int g    = lane >> 3;             // v index 0..7
        const int i8   = lane & 7;              // d-chunk: floats i8*16..+15

        for (int r = 0; r < 8; ++r) {
            const int row   = w * 8 + r;
            const size_t bh = (size_t)(b0 + row) * H_ + h;
            const float* vp = view + (bh * V_ + g) * DH_ + i8 * 16;
            const float* qp = &row_s[row][i8 * 16];
            const float4 x0 = *(const float4*)(vp + 0);
            const float4 x1 = *(const float4*)(vp + 4);
            const float4 x2 = *(const float4*)(vp + 8);
            const float4 x3 = *(const float4*)(vp + 12);
            const float4 q0 = *(const float4*)(qp + 0);
            const float4 q1 = *(const float4*)(qp + 4);
            const float4 q2 = *(const float4*)(qp + 8);
            const float4 q3 = *(const float4*)(qp + 12);
            float s = x0.x*q0.x + x0.y*q0.y + x0.z*q0.z + x0.w*q0.w
                    + x1.x*q1.x + x1.y*q1.y + x1.z*q1.z + x1.w*q1.w
                    + x2.x*q2.x + x2.y*q2.y + x2.z*q2.z + x2.w*q2.w
                    + x3.x*q3.x + x3.y*q3.y + x3.z*q3.z + x3.w*q3.w;
            // dot reduce over the 8 i8-lanes of this v-group
            s += __shfl_xor(s, 1);
            s += __shfl_xor(s, 2);
            s += __shfl_xor(s, 4);
            if (i8 == 0) {                      // 8 lanes, one per v
                float sc = s * 0.08838834764831845f
                         + logf(pi[bh * V_ + g] + 1e-6f);
                float mx = sc;
                mx = fmaxf(mx, __shfl_xor(mx, 8));
                mx = fmaxf(mx, __shfl_xor(mx, 16));
                mx = fmaxf(mx, __shfl_xor(mx, 32));
                const float ex = expf(sc - mx);
                float den = ex;
                den += __shfl_xor(den, 8);
                den += __shfl_xor(den, 16);
                den += __shfl_xor(den, 32);
                const float at = ex / den;
                at_s[row][g] = at;
                attn_out[bh * V_ + g] = at;
            }
        }

        // ctx: rows in pairs, lanes = 2 rows x 32 col-quads; view re-read hits L1
        const int half = lane >> 5;
        const int c    = lane & 31;
#pragma unroll
        for (int t = 0; t < 4; ++t) {
            const int row   = w * 8 + t * 2 + half;
            const size_t bh = (size_t)(b0 + row) * H_ + h;
            const float* vb = view + bh * V_ * DH_ + c * 4;
            float4 cx = make_float4(0.f, 0.f, 0.f, 0.f);
#pragma unroll
            for (int v = 0; v < V_; ++v) {
                const float a  = at_s[row][v];               // LDS broadcast
                const float4 x = *(const float4*)(vb + (size_t)v * DH_);
                cx.x += a * x.x; cx.y += a * x.y; cx.z += a * x.z; cx.w += a * x.w;
            }
            *(float4*)&row_s[row][c * 4] = cx;               // ctx overwrites qk
        }
    }
    __syncthreads();                            // all waves done with M-hi + middle

    // ---- stage NT-lo (rows 0..63)
#pragma unroll
    for (int i = 0; i < 8; ++i) {
        const int idx = tid + i * 256;
        *(float4*)&wbuf[idx * 4] = *(const float4*)(Nh + (size_t)idx * 4);
    }
    __syncthreads();

#pragma unroll
    for (int i = 0; i < 4; ++i)
#pragma unroll
        for (int j = 0; j < 4; ++j) acc[i][j] = 0.f;

    // ---- phase 3a: ctx cols 0..63 x NT rows 0..63
    mac64(0);
    __syncthreads();                            // done reading NT-lo

    // ---- stage NT-hi (rows 64..127)
#pragma unroll
    for (int i = 0; i < 8; ++i) {
        const int idx = tid + i * 256;
        *(float4*)&wbuf[idx * 4] = *(const float4*)(Nh + 8192 + (size_t)idx * 4);
    }
    __syncthreads();

    // ---- phase 3b: ctx cols 64..127 x NT rows 64..127
    mac64(64);

    // ---- store out
#pragma unroll
    for (int i = 0; i < 4; ++i)
        *(float4*)(out + ((size_t)(b0 + ty * 4 + i) * H_ + h) * DH_ + tx * 4) =
            make_float4(acc[i][0], acc[i][1], acc[i][2], acc[i][3]);
}

// ---------------------------------------------------------------------------
extern "C" void kernel_launch(void* const* d_in, const int* in_sizes, int n_in,
                              void* d_out, int out_size, void* d_ws, size_t ws_size,
                              hipStream_t stream)
{
    const float* iso  = (const float*)d_in[0];   // [B,H,DH]
    const float* view = (const float*)d_in[1];   // [B,H,V,DH]
    const float* pi   = (const float*)d_in[2];   // [B,H,V]
    const float* Wq   = (const float*)d_in[3];   // [H,DH,DH]
    const float* Wk   = (const float*)d_in[4];
    const float* Wv   = (const float*)d_in[5];
    const float* Wo   = (const float*)d_in[6];

    float* out  = (float*)d_out;                           // [B,H,DH]
    float* attn = out + (size_t)B_ * H_ * DH_;             // [B,H,V]

    float* Mmat  = (float*)d_ws;                           // H*DH*DH floats (1 MB)
    float* NTmat = Mmat + (size_t)H_ * DH_ * DH_;          // H*DH*DH floats (1 MB)

    hipLaunchKernelGGL(precompute_MN, dim3(2048), dim3(256), 0, stream,
                       Wq, Wk, Wv, Wo, Mmat, NTmat);
    hipLaunchKernelGGL(fused_attn, dim3(H_ * (B_ / BT)), dim3(256), 0, stream,
                       iso, view, pi, Mmat, NTmat, out, attn);
}

// Round 3
// 422.055 us; speedup vs baseline: 1.2300x; 1.1488x over previous
//
#include <hip/hip_runtime.h>
#include <cstdint>
#include <cstddef>

#define H_  16
#define V_  8
#define DH_ 128
#define B_  4096
#define BT  32

#define LDW 136   // padded row stride (halves) for f16 LDS tiles (+16B: bank spread)
#define LDQ 132   // padded row stride (floats) for qk tile

typedef _Float16 v8h __attribute__((ext_vector_type(8)));
typedef _Float16 v4h __attribute__((ext_vector_type(4)));
typedef float    v4f __attribute__((ext_vector_type(4)));

// ---------------------------------------------------------------------------
// Kernel A: MT16[h][dp][d] = sum_e Wq[e][d]*Wk[e][dp]      (f16, = M^T)
//           N216[h][e][dp] = sum_d Wo[e][d]*Wv[d][dp]      (f16, = Wo@Wv)
// Layouts chosen so fused-kernel B-fragments (k-contiguous per lane) are
// single ds_read_b128 from row-major LDS tiles.
// ---------------------------------------------------------------------------
__global__ __launch_bounds__(256) void precompute_MN(
    const float* __restrict__ Wq, const float* __restrict__ Wk,
    const float* __restrict__ Wv, const float* __restrict__ Wo,
    _Float16* __restrict__ MT16, _Float16* __restrict__ N216)
{
    const int bx    = blockIdx.x;
    const int which = bx & 1;
    const int h     = (bx >> 1) & 15;
    const int chunk = bx >> 5;                // 0..63
    const int tid   = threadIdx.x;
    const int col   = tid & 127;
    const int r     = chunk * 2 + (tid >> 7); // 0..127

    float acc = 0.f;
    if (which == 0) {
        const float* wq = Wq + h * DH_ * DH_;
        const float* wk = Wk + h * DH_ * DH_;
#pragma unroll 8
        for (int e = 0; e < DH_; ++e)
            acc += wq[e * DH_ + col] * wk[e * DH_ + r];   // coalesced * uniform
        MT16[(size_t)h * DH_ * DH_ + r * DH_ + col] = (_Float16)acc;
    } else {
        const float* wo = Wo + h * DH_ * DH_;
        const float* wv = Wv + h * DH_ * DH_;
#pragma unroll 8
        for (int d = 0; d < DH_; ++d)
            acc += wo[r * DH_ + d] * wv[d * DH_ + col];   // uniform * coalesced
        N216[(size_t)h * DH_ * DH_ + r * DH_ + col] = (_Float16)acc;
    }
}

// ---------------------------------------------------------------------------
// Kernel B: fused pipeline with MFMA for both 128x128 matmuls.
//   phase1: qk(32x128,f32) = iso16 @ M  via mfma_f32_16x16x32_f16
//   middle: scores/softmax/ctx, view read ONCE (coalesced, reg-resident)
//   phase3: out = ctx16 @ N2 via mfma
// 256 thr (4 waves); wave w: row-tile rt=w>>1 (16 rows), cols (w&1)*64..+63.
// LDS 60.4 KB -> 2 blocks/CU. 3 barriers.
// ---------------------------------------------------------------------------
__global__ __launch_bounds__(256, 2) void fused_attn(
    const float* __restrict__ iso, const float* __restrict__ view,
    const float* __restrict__ pi,
    const _Float16* __restrict__ MT16, const _Float16* __restrict__ N216,
    float* __restrict__ out, float* __restrict__ attn_out)
{
    __shared__ __align__(16) _Float16 w16[128 * LDW];  // M^T, then N2 (B-operand)
    __shared__ __align__(16) _Float16 a16[BT * LDW];   // iso16, then ctx16 (A-operand)
    __shared__ __align__(16) float    qk_s[BT * LDQ];  // qk f32 for the middle

    const int tid = threadIdx.x;
    const int h   = blockIdx.x >> 7;            // 128 b-tiles per head
    const int b0  = (blockIdx.x & 127) * BT;

    const int w    = tid >> 6;                  // wave 0..3
    const int lane = tid & 63;
    const int rt   = w >> 1;                    // row-tile (16 rows)
    const int cb   = (w & 1) * 64;              // col base
    const int fr   = lane & 15;                 // fragment row/col
    const int kg   = lane >> 4;                 // k-group 0..3

    // ---- stage iso -> a16 (cvt f32->f16), MT16 -> w16
#pragma unroll
    for (int i = 0; i < 4; ++i) {
        const int idx = tid + i * 256;          // 1024 float4
        const int r   = idx >> 5, c4 = idx & 31;
        const float4 t = *(const float4*)(iso + ((size_t)(b0 + r) * H_ + h) * DH_ + c4 * 4);
        v4h ht; ht[0] = (_Float16)t.x; ht[1] = (_Float16)t.y;
                ht[2] = (_Float16)t.z; ht[3] = (_Float16)t.w;
        *(v4h*)&a16[r * LDW + c4 * 4] = ht;
    }
    {
        const _Float16* src = MT16 + (size_t)h * DH_ * DH_;
#pragma unroll
        for (int i = 0; i < 8; ++i) {
            const int idx = tid + i * 256;      // 2048 chunks of 8 halves
            *(v8h*)&w16[(idx >> 4) * LDW + (idx & 15) * 8] = *(const v8h*)(src + idx * 8);
        }
    }
    __syncthreads();

    // ---- phase 1: qk = iso @ M  (A=a16, B=w16 rows are M^T[d'][d])
    {
        v4f ac0 = {0,0,0,0}, ac1 = {0,0,0,0}, ac2 = {0,0,0,0}, ac3 = {0,0,0,0};
#pragma unroll
        for (int kt = 0; kt < 4; ++kt) {
            const int ko = kt * 32 + kg * 8;
            const v8h a  = *(const v8h*)&a16[(rt * 16 + fr) * LDW + ko];
            const v8h bf0 = *(const v8h*)&w16[(cb +  0 + fr) * LDW + ko];
            const v8h bf1 = *(const v8h*)&w16[(cb + 16 + fr) * LDW + ko];
            const v8h bf2 = *(const v8h*)&w16[(cb + 32 + fr) * LDW + ko];
            const v8h bf3 = *(const v8h*)&w16[(cb + 48 + fr) * LDW + ko];
            ac0 = __builtin_amdgcn_mfma_f32_16x16x32_f16(a, bf0, ac0, 0, 0, 0);
            ac1 = __builtin_amdgcn_mfma_f32_16x16x32_f16(a, bf1, ac1, 0, 0, 0);
            ac2 = __builtin_amdgcn_mfma_f32_16x16x32_f16(a, bf2, ac2, 0, 0, 0);
            ac3 = __builtin_amdgcn_mfma_f32_16x16x32_f16(a, bf3, ac3, 0, 0, 0);
        }
        // C/D layout: col = lane&15, row = (lane>>4)*4 + reg
#pragma unroll
        for (int g = 0; g < 4; ++g) {
            const int row = rt * 16 + kg * 4 + g;
            qk_s[row * LDQ + cb +  0 + fr] = ac0[g];
            qk_s[row * LDQ + cb + 16 + fr] = ac1[g];
            qk_s[row * LDQ + cb + 32 + fr] = ac2[g];
            qk_s[row * LDQ + cb + 48 + fr] = ac3[g];
        }
    }
    __syncthreads();    // qk ready; all reads of a16(iso)/w16(MT) done

    // ---- stage N216 -> w16 early (latency hides under the middle phase)
    {
        const _Float16* src = N216 + (size_t)h * DH_ * DH_;
#pragma unroll
        for (int i = 0; i < 8; ++i) {
            const int idx = tid + i * 256;
            *(v8h*)&w16[(idx >> 4) * LDW + (idx & 15) * 8] = *(const v8h*)(src + idx * 8);
        }
    }

    // ---- middle: wave w owns rows 8w..8w+7. view read once, coalesced.
    {
        const int hl  = lane >> 5;              // parity: lane half
        const int l32 = lane & 31;              // d-chunk (l32*4..+3)
        const float SC = 0.08838834764831845f;  // 1/sqrt(128)

        const float* vb = view + ((size_t)(b0 + w * 8) * H_ + h) * (V_ * DH_);
        float4 x0 = *(const float4*)(vb +   0 + lane * 4);
        float4 x1 = *(const float4*)(vb + 256 + lane * 4);
        float4 x2 = *(const float4*)(vb + 512 + lane * 4);
        float4 x3 = *(const float4*)(vb + 768 + lane * 4);

#pragma unroll
        for (int r = 0; r < 8; ++r) {
            const int row   = w * 8 + r;
            const size_t bh = (size_t)(b0 + row) * H_ + h;

            const v4f q4 = *(const v4f*)&qk_s[row * LDQ + l32 * 4];
            // partial dots; inst j holds v = 2j + hl, d-chunk = l32*4
            float p0 = x0.x*q4[0] + x0.y*q4[1] + x0.z*q4[2] + x0.w*q4[3];
            float p1 = x1.x*q4[0] + x1.y*q4[1] + x1.z*q4[2] + x1.w*q4[3];
            float p2 = x2.x*q4[0] + x2.y*q4[1] + x2.z*q4[2] + x2.w*q4[3];
            float p3 = x3.x*q4[0] + x3.y*q4[1] + x3.z*q4[2] + x3.w*q4[3];

            // prefetch next row (keeps ~8KB/wave in flight toward HBM)
            float4 y0, y1, y2, y3;
            if (r < 7) {
                const float* vn = vb + H_ * V_ * DH_;
                y0 = *(const float4*)(vn +   0 + lane * 4);
                y1 = *(const float4*)(vn + 256 + lane * 4);
                y2 = *(const float4*)(vn + 512 + lane * 4);
                y3 = *(const float4*)(vn + 768 + lane * 4);
            }

            // reduce each dot over its 32-lane half
            p0 += __shfl_xor(p0, 1); p0 += __shfl_xor(p0, 2); p0 += __shfl_xor(p0, 4);
            p0 += __shfl_xor(p0, 8); p0 += __shfl_xor(p0, 16);
            p1 += __shfl_xor(p1, 1); p1 += __shfl_xor(p1, 2); p1 += __shfl_xor(p1, 4);
            p1 += __shfl_xor(p1, 8); p1 += __shfl_xor(p1, 16);
            p2 += __shfl_xor(p2, 1); p2 += __shfl_xor(p2, 2); p2 += __shfl_xor(p2, 4);
            p2 += __shfl_xor(p2, 8); p2 += __shfl_xor(p2, 16);
            p3 += __shfl_xor(p3, 1); p3 += __shfl_xor(p3, 2); p3 += __shfl_xor(p3, 4);
            p3 += __shfl_xor(p3, 8); p3 += __shfl_xor(p3, 16);
            // opposite-parity sums
            const float o0 = __shfl_xor(p0, 32);
            const float o1 = __shfl_xor(p1, 32);
            const float o2 = __shfl_xor(p2, 32);
            const float o3 = __shfl_xor(p3, 32);

            // pi (broadcast, L1-hot); softmax(s/sqrt(d)+log(pi+eps)) ==
            // (pi+eps)*exp(s/sqrt(d)-m) normalized -> no logf needed
            const float4 pa = *(const float4*)(pi + bh * V_);
            const float4 pb = *(const float4*)(pi + bh * V_ + 4);
            const float pe0 = hl ? pa.y : pa.x,  po0 = hl ? pa.x : pa.y;
            const float pe1 = hl ? pa.w : pa.z,  po1 = hl ? pa.z : pa.w;
            const float pe2 = hl ? pb.y : pb.x,  po2 = hl ? pb.x : pb.y;
            const float pe3 = hl ? pb.w : pb.z,  po3 = hl ? pb.z : pb.w;

            const float s0 = p0 * SC, s1 = p1 * SC, s2 = p2 * SC, s3 = p3 * SC;
            const float t0 = o0 * SC, t1 = o1 * SC, t2 = o2 * SC, t3 = o3 * SC;
            const float m  = fmaxf(fmaxf(fmaxf(s0, s1), fmaxf(s2, s3)),
                                   fmaxf(fmaxf(t0, t1), fmaxf(t2, t3)));
            const float e0 = (pe0 + 1e-6f) * __expf(s0 - m);
            const float e1 = (pe1 + 1e-6f) * __expf(s1 - m);
            const float e2 = (pe2 + 1e-6f) * __expf(s2 - m);
            const float e3 = (pe3 + 1e-6f) * __expf(s3 - m);
            const float f0 = (po0 + 1e-6f) * __expf(t0 - m);
            const float f1 = (po1 + 1e-6f) * __expf(t1 - m);
            const float f2 = (po2 + 1e-6f) * __expf(t2 - m);
            const float f3 = (po3 + 1e-6f) * __expf(t3 - m);
            const float inv = 1.0f / (((e0 + e1) + (e2 + e3)) + ((f0 + f1) + (f2 + f3)));
            const float a0 = e0 * inv, a1 = e1 * inv, a2 = e2 * inv, a3 = e3 * inv;

            // ctx partial over own parity, then cross-parity add
            float cx = a0 * x0.x + a1 * x1.x + a2 * x2.x + a3 * x3.x;
            float cy = a0 * x0.y + a1 * x1.y + a2 * x2.y + a3 * x3.y;
            float cz = a0 * x0.z + a1 * x1.z + a2 * x2.z + a3 * x3.z;
            float cw = a0 * x0.w + a1 * x1.w + a2 * x2.w + a3 * x3.w;
            cx += __shfl_xor(cx, 32);
            cy += __shfl_xor(cy, 32);
            cz += __shfl_xor(cz, 32);
            cw += __shfl_xor(cw, 32);
            if (lane < 32) {
                v4h ch; ch[0] = (_Float16)cx; ch[1] = (_Float16)cy;
                        ch[2] = (_Float16)cz; ch[3] = (_Float16)cw;
                *(v4h*)&a16[row * LDW + l32 * 4] = ch;      // ctx16 over dead iso16
            }
            if (l32 == 0) {                                  // lanes 0 and 32
                float* ao = attn_out + bh * V_;
                ao[0 + hl] = a0; ao[2 + hl] = a1; ao[4 + hl] = a2; ao[6 + hl] = a3;
            }
            if (r < 7) { vb += H_ * V_ * DH_; x0 = y0; x1 = y1; x2 = y2; x3 = y3; }
        }
    }
    __syncthreads();    // ctx16 + N216 staged

    // ---- phase 3: out = ctx @ N2  (B rows are N2[e][d'] -> k=d' contiguous)
    {
        v4f ac0 = {0,0,0,0}, ac1 = {0,0,0,0}, ac2 = {0,0,0,0}, ac3 = {0,0,0,0};
#pragma unroll
        for (int kt = 0; kt < 4; ++kt) {
            const int ko = kt * 32 + kg * 8;
            const v8h a  = *(const v8h*)&a16[(rt * 16 + fr) * LDW + ko];
            const v8h bf0 = *(const v8h*)&w16[(cb +  0 + fr) * LDW + ko];
            const v8h bf1 = *(const v8h*)&w16[(cb + 16 + fr) * LDW + ko];
            const v8h bf2 = *(const v8h*)&w16[(cb + 32 + fr) * LDW + ko];
            const v8h bf3 = *(const v8h*)&w16[(cb + 48 + fr) * LDW + ko];
            ac0 = __builtin_amdgcn_mfma_f32_16x16x32_f16(a, bf0, ac0, 0, 0, 0);
            ac1 = __builtin_amdgcn_mfma_f32_16x16x32_f16(a, bf1, ac1, 0, 0, 0);
            ac2 = __builtin_amdgcn_mfma_f32_16x16x32_f16(a, bf2, ac2, 0, 0, 0);
            ac3 = __builtin_amdgcn_mfma_f32_16x16x32_f16(a, bf3, ac3, 0, 0, 0);
        }
#pragma unroll
        for (int g = 0; g < 4; ++g) {
            float* op = out + (size_t)(b0 + rt * 16 + kg * 4 + g) * (H_ * DH_) + h * DH_;
            op[cb +  0 + fr] = ac0[g];
            op[cb + 16 + fr] = ac1[g];
            op[cb + 32 + fr] = ac2[g];
            op[cb + 48 + fr] = ac3[g];
        }
    }
}

// ---------------------------------------------------------------------------
extern "C" void kernel_launch(void* const* d_in, const int* in_sizes, int n_in,
                              void* d_out, int out_size, void* d_ws, size_t ws_size,
                              hipStream_t stream)
{
    const float* iso  = (const float*)d_in[0];   // [B,H,DH]
    const float* view = (const float*)d_in[1];   // [B,H,V,DH]
    const float* pi   = (const float*)d_in[2];   // [B,H,V]
    const float* Wq   = (const float*)d_in[3];   // [H,DH,DH]
    const float* Wk   = (const float*)d_in[4];
    const float* Wv   = (const float*)d_in[5];
    const float* Wo   = (const float*)d_in[6];

    float* out  = (float*)d_out;                           // [B,H,DH]
    float* attn = out + (size_t)B_ * H_ * DH_;             // [B,H,V]

    _Float16* MT16 = (_Float16*)d_ws;                      // 512 KB
    _Float16* N216 = MT16 + (size_t)H_ * DH_ * DH_;        // 512 KB

    hipLaunchKernelGGL(precompute_MN, dim3(2048), dim3(256), 0, stream,
                       Wq, Wk, Wv, Wo, MT16, N216);
    hipLaunchKernelGGL(fused_attn, dim3(H_ * (B_ / BT)), dim3(256), 0, stream,
                       iso, view, pi, MT16, N216, out, attn);
}